// Round 4
// baseline (97.776 us; speedup 1.0000x reference)
//
#include <hip/hip_runtime.h>
#include <hip/hip_bf16.h>
#include <cfloat>

#define BB 16
#define NN 512
#define DIMX 78
#define VTS 80                     // padded vT row stride
#define NH 6
#define DHH 13
#define NC (NH*3*DHH)              // 234
#define SCALE 0.27735009811261457f // 13^-0.5
#define LAM_A 1.0f
#define LAM_G 0.5f
#define NU 32

typedef unsigned short ushortx;
typedef ushortx ushort8 __attribute__((ext_vector_type(8)));

__device__ __forceinline__ ushortx f2bf(float f) {
  unsigned u = __float_as_uint(f);
  unsigned r = (u + 0x7FFFu + ((u >> 16) & 1u)) >> 16;
  return (ushortx)r;
}
__device__ __forceinline__ float bf2f(ushortx h) {
  return __uint_as_float(((unsigned)h) << 16);
}

// ---------------- QKV projection: (B*N, 78) @ (78, 234) ----------------
// thread = 4 rows x 4 cols register tile. Also emits vT[b,n,VTS] (n-major,
// cols h*13+d), zeroed where mask[b,n]==0, for the adjacency GEMM.
__global__ __launch_bounds__(256) void qkv_kernel(
    const float* __restrict__ x, const float* __restrict__ Wqkv,
    const int* __restrict__ mask,
    float* __restrict__ q, float* __restrict__ k, float* __restrict__ v,
    float* __restrict__ vT) {
  int idx = blockIdx.x * 256 + threadIdx.x;
  const int NQ = 59;
  int rq = idx / NQ, cq = idx % NQ;
  if (rq >= (BB * NN) / 4) return;
  int c0 = cq * 4; if (c0 > NC - 4) c0 = NC - 4;
  int r0 = rq * 4;
  const float* x0 = x + (size_t)r0 * DIMX;

  float acc[4][4];
#pragma unroll
  for (int r = 0; r < 4; ++r)
#pragma unroll
    for (int c = 0; c < 4; ++c) acc[r][c] = 0.f;

#pragma unroll 6
  for (int d = 0; d < DIMX; ++d) {
    float w0 = Wqkv[d * NC + c0 + 0];
    float w1 = Wqkv[d * NC + c0 + 1];
    float w2 = Wqkv[d * NC + c0 + 2];
    float w3 = Wqkv[d * NC + c0 + 3];
#pragma unroll
    for (int r = 0; r < 4; ++r) {
      float xv = x0[r * DIMX + d];
      acc[r][0] = fmaf(xv, w0, acc[r][0]);
      acc[r][1] = fmaf(xv, w1, acc[r][1]);
      acc[r][2] = fmaf(xv, w2, acc[r][2]);
      acc[r][3] = fmaf(xv, w3, acc[r][3]);
    }
  }
#pragma unroll
  for (int r = 0; r < 4; ++r) {
    int bn = r0 + r;
    int b = bn / NN, n = bn % NN;
    bool mb = mask[bn] != 0;
#pragma unroll
    for (int c = 0; c < 4; ++c) {
      int col = c0 + c;
      int h  = col / (3 * DHH);
      int rm = col % (3 * DHH);
      int t  = rm / DHH;
      int dd = rm % DHH;
      float* dst = (t == 0) ? q : ((t == 1) ? k : v);
      dst[(((size_t)b * NH + h) * NN + n) * DHH + dd] = acc[r][c];
      if (t == 2)
        vT[(size_t)bn * VTS + h * DHH + dd] = mb ? acc[r][c] : 0.f;
    }
  }
}

// ---------------- vT padding init (cols 78,79) ----------------
__global__ __launch_bounds__(256) void vtpad_kernel(float* __restrict__ vT) {
  int i = blockIdx.x * 256 + threadIdx.x;
  if (i < BB * NN) { vT[(size_t)i * VTS + 78] = 0.f; vT[(size_t)i * VTS + 79] = 0.f; }
}

// ---------------- Adjacency GEMM: att_adj[b,i,:] = 0.5 * adj[b,i,:] @ vT ----
// grid = B * (N/16) = 512 blocks; 256 threads.
// thread = (js j-slice, s col-strip of 20, rq row-quad): 4 rows x 20 cols tile.
#define RT 16
__global__ __launch_bounds__(256) void adjv_kernel(
    const float* __restrict__ vT, const int* __restrict__ mask,
    const float* __restrict__ adj, float* __restrict__ att_adj) {
  __shared__ float adjs[RT][66];
  __shared__ float vs[64][VTS];
  __shared__ float part[4][RT][VTS];

  int blk = blockIdx.x;
  int b   = blk / (NN / RT);
  int it  = blk % (NN / RT);
  int i0  = it * RT;
  int tid = threadIdx.x;
  int js  = tid >> 4;
  int s   = (tid >> 2) & 3;
  int rq  = tid & 3;
  int c0  = s * 20;

  const float* adjb = adj + ((size_t)b * NN + i0) * NN;
  const float* vTb  = vT + (size_t)b * NN * VTS;

  float acc[4][20];
#pragma unroll
  for (int r = 0; r < 4; ++r)
#pragma unroll
    for (int c = 0; c < 20; ++c) acc[r][c] = 0.f;

  for (int chunk = 0; chunk < 8; ++chunk) {
    int j0 = chunk * 64;
    // stage adj tile [16][64], coalesced float4
    {
      int rr = tid >> 4, jj = (tid & 15) * 4;
      const float4 val = *(const float4*)(adjb + (size_t)rr * NN + j0 + jj);
      adjs[rr][jj + 0] = val.x; adjs[rr][jj + 1] = val.y;
      adjs[rr][jj + 2] = val.z; adjs[rr][jj + 3] = val.w;
    }
    // stage vT chunk [64][80], coalesced float4 (5 per thread)
    {
      const float4* src = (const float4*)(vTb + (size_t)j0 * VTS);
      float4* dstv = (float4*)(&vs[0][0]);
#pragma unroll
      for (int kq = 0; kq < 5; ++kq) dstv[tid + kq * 256] = src[tid + kq * 256];
    }
    __syncthreads();
#pragma unroll
    for (int t = 0; t < 4; ++t) {
      int jl = js * 4 + t;
      float a0 = adjs[rq * 4 + 0][jl];
      float a1 = adjs[rq * 4 + 1][jl];
      float a2 = adjs[rq * 4 + 2][jl];
      float a3 = adjs[rq * 4 + 3][jl];
#pragma unroll
      for (int c = 0; c < 20; ++c) {
        float vv = vs[jl][c0 + c];
        acc[0][c] = fmaf(a0, vv, acc[0][c]);
        acc[1][c] = fmaf(a1, vv, acc[1][c]);
        acc[2][c] = fmaf(a2, vv, acc[2][c]);
        acc[3][c] = fmaf(a3, vv, acc[3][c]);
      }
    }
    __syncthreads();
  }

  // butterfly-reduce over the 4 j-slices living in lane bits [5:4]
#pragma unroll
  for (int r = 0; r < 4; ++r)
#pragma unroll
    for (int c = 0; c < 20; ++c) {
      acc[r][c] += __shfl_xor(acc[r][c], 16);
      acc[r][c] += __shfl_xor(acc[r][c], 32);
    }
  int wv = tid >> 6;
  if (((tid >> 4) & 3) == 0) {
#pragma unroll
    for (int r = 0; r < 4; ++r)
#pragma unroll
      for (int c = 0; c < 20; c += 4)
        *(float4*)(&part[wv][rq * 4 + r][c0 + c]) = *(float4*)(&acc[r][c]);
  }
  __syncthreads();

  const int* mrow = mask + b * NN;
  for (int e = tid; e < RT * DIMX; e += 256) {
    int rr = e / DIMX, c = e % DIMX;
    float sv = part[0][rr][c] + part[1][rr][c] + part[2][rr][c] + part[3][rr][c];
    att_adj[((size_t)b * NN + i0 + rr) * DIMX + c] =
        (mrow[i0 + rr] != 0) ? LAM_G * sv : 0.f;
  }
}

// ---------------- Fused masked softmax attention (compacted, bf16 LDS) ----
__global__ __launch_bounds__(256, 4) void attn_kernel(
    const float* __restrict__ q, const float* __restrict__ k,
    const float* __restrict__ v, const int* __restrict__ mask,
    float* __restrict__ att) {
  __shared__ ushort8 k0s[NN], k1s[NN];
  __shared__ ushort8 v0s[NN], v1s[NN];
  __shared__ short jact[NN];
  __shared__ unsigned char ract[64];
  __shared__ float vsum[DHH];
  __shared__ int nact_s, nract_s;

  int blk   = blockIdx.x;
  int itile = blk & 7;
  int bh    = blk >> 3;
  int b     = bh / NH;
  int h     = bh % NH;
  int i0    = itile * 64;

  const float* kb = k + (size_t)bh * NN * DHH;
  const float* vb = v + (size_t)bh * NN * DHH;
  const int* mrow = mask + b * NN;

  int tid  = threadIdx.x;
  int wave = tid >> 6, lane = tid & 63;

  if (wave == 0) {
    unsigned m8 = 0;
#pragma unroll
    for (int t = 0; t < 8; ++t) {
      int j = lane * 8 + t;
      if (mrow[j] != 0) m8 |= (1u << t);
    }
    int cnt = __popc(m8);
    int pre = cnt;
#pragma unroll
    for (int off = 1; off < 64; off <<= 1) {
      int o = __shfl_up(pre, off);
      if (lane >= off) pre += o;
    }
    pre -= cnt;
    int w = pre;
#pragma unroll
    for (int t = 0; t < 8; ++t)
      if ((m8 >> t) & 1) jact[w++] = (short)(lane * 8 + t);
    if (lane == 63) nact_s = pre + cnt;
  } else if (wave == 1) {
    int a = (mrow[i0 + lane] != 0) ? 1 : 0;
    int pre = a;
#pragma unroll
    for (int off = 1; off < 64; off <<= 1) {
      int o = __shfl_up(pre, off);
      if (lane >= off) pre += o;
    }
    pre -= a;
    if (a) ract[pre] = (unsigned char)lane;
    if (lane == 63) nract_s = pre + a;
  } else if (wave == 2) {
    int d = lane % DHH;
    int part = lane / DHH;
    float sacc = 0.f;
    if (part < 4) {
      for (int n = part * 128; n < (part + 1) * 128; ++n)
        sacc += vb[n * DHH + d];
    }
    float t1 = __shfl(sacc, d + DHH);
    float t2 = __shfl(sacc, d + 2 * DHH);
    float t3 = __shfl(sacc, d + 3 * DHH);
    if (lane < DHH) vsum[lane] = sacc + t1 + t2 + t3;
  }
  __syncthreads();

  int na = nact_s;
  int nr = nract_s;

  for (int t = tid; t < NN; t += 256) {
    if (t < na) {
      int j = jact[t];
      const float* kr = kb + j * DHH;
      const float* vr = vb + j * DHH;
      ushort8 a0, a1, c0v, c1;
#pragma unroll
      for (int d = 0; d < 8; ++d) { a0[d] = f2bf(kr[d]); c0v[d] = f2bf(vr[d]); }
#pragma unroll
      for (int d = 0; d < 5; ++d) { a1[d] = f2bf(kr[8 + d]); c1[d] = f2bf(vr[8 + d]); }
#pragma unroll
      for (int d = 5; d < 8; ++d) { a1[d] = 0; c1[d] = 0; }
      k0s[t] = a0; k1s[t] = a1; v0s[t] = c0v; v1s[t] = c1;
    } else {
      ushort8 z = (ushort8)0;
      k0s[t] = z; k1s[t] = z; v0s[t] = z; v1s[t] = z;
    }
  }
  for (int e = tid; e < 64 * DHH; e += 256) {
    int r = e / DHH, d = e % DHH;
    int i = i0 + r;
    if (mrow[i] == 0)
      att[((size_t)b * NN + i) * DIMX + h * DHH + d] = (LAM_A / 512.f) * vsum[d];
  }
  __syncthreads();

  int grp = lane >> 4;
  int li  = lane & 15;

  for (int base = wave * 4; base < nr; base += 16) {
    int ridx = base + grp;
    bool rok = ridx < nr;
    int i = i0 + ract[rok ? ridx : 0];
    const float* qi = q + ((size_t)bh * NN + i) * DHH;
    float qreg[DHH];
#pragma unroll
    for (int d = 0; d < DHH; ++d) qreg[d] = qi[d] * SCALE;

    float s[NU];
    float mx = -FLT_MAX;
#pragma unroll
    for (int u = 0; u < NU; ++u) {
      if (u * 16 < na) {
        int t = u * 16 + li;
        ushort8 ka = k0s[t];
        ushort8 kc = k1s[t];
        float dot = 0.f;
#pragma unroll
        for (int d = 0; d < 8; ++d) dot = fmaf(qreg[d], bf2f(ka[d]), dot);
#pragma unroll
        for (int d = 0; d < 5; ++d) dot = fmaf(qreg[8 + d], bf2f(kc[d]), dot);
        s[u] = (t < na) ? dot : -FLT_MAX;
        mx = fmaxf(mx, s[u]);
      }
    }
#pragma unroll
    for (int off = 1; off < 16; off <<= 1) mx = fmaxf(mx, __shfl_xor(mx, off));

    float sum = 0.f;
#pragma unroll
    for (int u = 0; u < NU; ++u) {
      if (u * 16 < na) {
        float p = __expf(s[u] - mx);
        s[u] = p;
        sum += p;
      }
    }
#pragma unroll
    for (int off = 1; off < 16; off <<= 1) sum += __shfl_xor(sum, off);
    float inv = LAM_A / sum;

    float acc[DHH];
#pragma unroll
    for (int d = 0; d < DHH; ++d) acc[d] = 0.f;
#pragma unroll
    for (int u = 0; u < NU; ++u) {
      if (u * 16 < na) {
        int t = u * 16 + li;
        ushort8 va = v0s[t];
        ushort8 vc = v1s[t];
        float wu = s[u];
#pragma unroll
        for (int d = 0; d < 8; ++d) acc[d] = fmaf(wu, bf2f(va[d]), acc[d]);
#pragma unroll
        for (int d = 0; d < 5; ++d) acc[8 + d] = fmaf(wu, bf2f(vc[d]), acc[8 + d]);
      }
    }
#pragma unroll
    for (int off = 1; off < 16; off <<= 1) {
#pragma unroll
      for (int d = 0; d < DHH; ++d) acc[d] += __shfl_xor(acc[d], off);
    }

    if (rok && li == 0) {
#pragma unroll
      for (int d = 0; d < DHH; ++d)
        att[((size_t)b * NN + i) * DIMX + h * DHH + d] = acc[d] * inv;
    }
  }
}

// ---------------- Output projection: (sm+adj)(B*N,78) @ (78,78) + b --------
__global__ __launch_bounds__(256) void proj_kernel(
    const float* __restrict__ att_sm, const float* __restrict__ att_adj,
    const float* __restrict__ Wout, const float* __restrict__ bout,
    float* __restrict__ out) {
  __shared__ float Ws[DIMX * DIMX];
  __shared__ float bs[DIMX];
  __shared__ float as[32][DIMX];
  for (int idx = threadIdx.x; idx < DIMX * DIMX; idx += 256) Ws[idx] = Wout[idx];
  if (threadIdx.x < DIMX) bs[threadIdx.x] = bout[threadIdx.x];
  size_t row0 = (size_t)blockIdx.x * 32;
  for (int idx = threadIdx.x; idx < 32 * DIMX; idx += 256)
    as[idx / DIMX][idx % DIMX] = att_sm[row0 * DIMX + idx] + att_adj[row0 * DIMX + idx];
  __syncthreads();
  for (int e = threadIdx.x; e < 32 * DIMX; e += 256) {
    int r = e / DIMX, c = e % DIMX;
    float acc = bs[c];
#pragma unroll
    for (int d = 0; d < DIMX; ++d) acc = fmaf(as[r][d], Ws[d * DIMX + c], acc);
    out[(row0 + r) * DIMX + c] = acc;
  }
}

extern "C" void kernel_launch(void* const* d_in, const int* in_sizes, int n_in,
                              void* d_out, int out_size, void* d_ws, size_t ws_size,
                              hipStream_t stream) {
  const float* x    = (const float*)d_in[0];
  const int*   mask = (const int*)d_in[1];
  const float* adj  = (const float*)d_in[2];
  const float* Wqkv = (const float*)d_in[3];
  const float* Wout = (const float*)d_in[4];
  const float* bout = (const float*)d_in[5];
  float* out = (float*)d_out;

  const size_t qkv_elems = (size_t)BB * NH * NN * DHH;  // 638,976
  const size_t bn78      = (size_t)BB * NN * DIMX;      // 638,976
  float* q       = (float*)d_ws;
  float* k       = q + qkv_elems;
  float* v       = k + qkv_elems;
  float* att_sm  = v + qkv_elems;
  float* att_adj = att_sm + bn78;
  float* vT      = att_adj + bn78;  // BB*NN*VTS

  const int NQ = 59;
  int qkv_threads = (BB * NN / 4) * NQ;
  vtpad_kernel<<<(BB * NN + 255) / 256, 256, 0, stream>>>(vT);
  qkv_kernel<<<(qkv_threads + 255) / 256, 256, 0, stream>>>(x, Wqkv, mask, q, k, v, vT);
  adjv_kernel<<<BB * (NN / RT), 256, 0, stream>>>(vT, mask, adj, att_adj);
  attn_kernel<<<BB * NH * (NN / 64), 256, 0, stream>>>(q, k, v, mask, att_sm);
  proj_kernel<<<BB * NN / 32, 256, 0, stream>>>(att_sm, att_adj, Wout, bout, out);
}

// Round 5
// 73.286 us; speedup vs baseline: 1.3342x; 1.3342x over previous
//
#include <hip/hip_runtime.h>
#include <hip/hip_bf16.h>
#include <cfloat>

#define BB 16
#define NN 512
#define DIMX 78
#define NH 6
#define DHH 13
#define QS 16                      // padded head-dim stride for q/k/v
#define NC (NH*3*DHH)              // 234
#define SCALE 0.27735009811261457f // 13^-0.5
#define LAM_A 1.0f
#define LAM_G 0.5f
#define NU 32

typedef unsigned short ushortx;
typedef ushortx ushort8 __attribute__((ext_vector_type(8)));

__device__ __forceinline__ ushortx f2bf(float f) {
  unsigned u = __float_as_uint(f);
  unsigned r = (u + 0x7FFFu + ((u >> 16) & 1u)) >> 16;
  return (ushortx)r;
}
__device__ __forceinline__ float bf2f(ushortx h) {
  return __uint_as_float(((unsigned)h) << 16);
}

// ---------------- QKV projection: (B*N, 78) @ (78, 234) ----------------
// thread = 4 rows x 4 cols register tile; outputs padded to stride QS=16.
__global__ __launch_bounds__(256) void qkv_kernel(
    const float* __restrict__ x, const float* __restrict__ Wqkv,
    float* __restrict__ q, float* __restrict__ k, float* __restrict__ v) {
  int idx = blockIdx.x * 256 + threadIdx.x;
  const int NQ = 59;
  int rq = idx / NQ, cq = idx % NQ;
  if (rq >= (BB * NN) / 4) return;
  int c0 = cq * 4; if (c0 > NC - 4) c0 = NC - 4;
  int r0 = rq * 4;
  const float* x0 = x + (size_t)r0 * DIMX;

  float acc[4][4];
#pragma unroll
  for (int r = 0; r < 4; ++r)
#pragma unroll
    for (int c = 0; c < 4; ++c) acc[r][c] = 0.f;

#pragma unroll 6
  for (int d = 0; d < DIMX; ++d) {
    float w0 = Wqkv[d * NC + c0 + 0];
    float w1 = Wqkv[d * NC + c0 + 1];
    float w2 = Wqkv[d * NC + c0 + 2];
    float w3 = Wqkv[d * NC + c0 + 3];
#pragma unroll
    for (int r = 0; r < 4; ++r) {
      float xv = x0[r * DIMX + d];
      acc[r][0] = fmaf(xv, w0, acc[r][0]);
      acc[r][1] = fmaf(xv, w1, acc[r][1]);
      acc[r][2] = fmaf(xv, w2, acc[r][2]);
      acc[r][3] = fmaf(xv, w3, acc[r][3]);
    }
  }
#pragma unroll
  for (int r = 0; r < 4; ++r) {
    int bn = r0 + r;
    int b = bn / NN, n = bn % NN;
#pragma unroll
    for (int c = 0; c < 4; ++c) {
      int col = c0 + c;
      int h  = col / (3 * DHH);
      int rm = col % (3 * DHH);
      int t  = rm / DHH;
      int dd = rm % DHH;
      float* dst = (t == 0) ? q : ((t == 1) ? k : v);
      dst[(((size_t)b * NH + h) * NN + n) * QS + dd] = acc[r][c];
    }
  }
}

// ---------------- Fused masked softmax attention (compacted, bf16 LDS) ----
// grid = B*H*(N/64) = 768 blocks; block = 256 (4 waves), 4 blocks/CU.
// Adjacency term fused into PV weight: wu = p*inv + 0.5*adj (gathers issued
// in the dot loop, consumed after softmax -> latency hidden).
__global__ __launch_bounds__(256, 4) void attn_kernel(
    const float* __restrict__ q, const float* __restrict__ k,
    const float* __restrict__ v, const int* __restrict__ mask,
    const float* __restrict__ adj, float* __restrict__ att) {
  __shared__ ushort8 k0s[NN], k1s[NN];
  __shared__ ushort8 v0s[NN], v1s[NN];
  __shared__ short jact[NN];
  __shared__ unsigned char ract[64];
  __shared__ float vsum[DHH];
  __shared__ int nact_s, nract_s;

  int blk   = blockIdx.x;
  int itile = blk & 7;
  int bh    = blk >> 3;
  int b     = bh / NH;
  int h     = bh % NH;
  int i0    = itile * 64;

  const float* kb = k + (size_t)bh * NN * QS;
  const float* vb = v + (size_t)bh * NN * QS;
  const int* mrow = mask + b * NN;

  int tid  = threadIdx.x;
  int wave = tid >> 6, lane = tid & 63;

  if (wave == 0) {
    unsigned m8 = 0;
#pragma unroll
    for (int t = 0; t < 8; ++t) {
      int j = lane * 8 + t;
      if (mrow[j] != 0) m8 |= (1u << t);
    }
    int cnt = __popc(m8);
    int pre = cnt;
#pragma unroll
    for (int off = 1; off < 64; off <<= 1) {
      int o = __shfl_up(pre, off);
      if (lane >= off) pre += o;
    }
    pre -= cnt;
    int w = pre;
#pragma unroll
    for (int t = 0; t < 8; ++t)
      if ((m8 >> t) & 1) jact[w++] = (short)(lane * 8 + t);
    if (lane == 63) nact_s = pre + cnt;
  } else if (wave == 1) {
    int a = (mrow[i0 + lane] != 0) ? 1 : 0;
    int pre = a;
#pragma unroll
    for (int off = 1; off < 64; off <<= 1) {
      int o = __shfl_up(pre, off);
      if (lane >= off) pre += o;
    }
    pre -= a;
    if (a) ract[pre] = (unsigned char)lane;
    if (lane == 63) nract_s = pre + a;
  } else if (wave == 2) {
    int d = lane % DHH;
    int part = lane / DHH;
    float sacc = 0.f;
    if (part < 4) {
      for (int n = part * 128; n < (part + 1) * 128; ++n)
        sacc += vb[n * QS + d];
    }
    float t1 = __shfl(sacc, d + DHH);
    float t2 = __shfl(sacc, d + 2 * DHH);
    float t3 = __shfl(sacc, d + 3 * DHH);
    if (lane < DHH) vsum[lane] = sacc + t1 + t2 + t3;
  }
  __syncthreads();

  int na = nact_s;
  int nr = nract_s;

  // stage compacted K,V as bf16 (vectorized source loads); zero tails
  for (int t = tid; t < NN; t += 256) {
    if (t < na) {
      int j = jact[t];
      const float4* kr4 = (const float4*)(kb + (size_t)j * QS);
      const float4* vr4 = (const float4*)(vb + (size_t)j * QS);
      float4 kf0 = kr4[0], kf1 = kr4[1], kf2 = kr4[2];
      float4 vf0 = vr4[0], vf1 = vr4[1], vf2 = vr4[2];
      float k12 = kb[(size_t)j * QS + 12];
      float v12 = vb[(size_t)j * QS + 12];
      ushort8 a0, a1, c0v, c1;
      a0[0]=f2bf(kf0.x); a0[1]=f2bf(kf0.y); a0[2]=f2bf(kf0.z); a0[3]=f2bf(kf0.w);
      a0[4]=f2bf(kf1.x); a0[5]=f2bf(kf1.y); a0[6]=f2bf(kf1.z); a0[7]=f2bf(kf1.w);
      a1[0]=f2bf(kf2.x); a1[1]=f2bf(kf2.y); a1[2]=f2bf(kf2.z); a1[3]=f2bf(kf2.w);
      a1[4]=f2bf(k12);   a1[5]=0; a1[6]=0; a1[7]=0;
      c0v[0]=f2bf(vf0.x); c0v[1]=f2bf(vf0.y); c0v[2]=f2bf(vf0.z); c0v[3]=f2bf(vf0.w);
      c0v[4]=f2bf(vf1.x); c0v[5]=f2bf(vf1.y); c0v[6]=f2bf(vf1.z); c0v[7]=f2bf(vf1.w);
      c1[0]=f2bf(vf2.x); c1[1]=f2bf(vf2.y); c1[2]=f2bf(vf2.z); c1[3]=f2bf(vf2.w);
      c1[4]=f2bf(v12);   c1[5]=0; c1[6]=0; c1[7]=0;
      k0s[t] = a0; k1s[t] = a1; v0s[t] = c0v; v1s[t] = c1;
    } else {
      ushort8 z = (ushort8)0;
      k0s[t] = z; k1s[t] = z; v0s[t] = z; v1s[t] = z;
      jact[t] = 0;
    }
  }
  // fully-masked rows: uniform softmax over all 512, zero adjacency
  for (int e = tid; e < 64 * DHH; e += 256) {
    int r = e / DHH, d = e % DHH;
    int i = i0 + r;
    if (mrow[i] == 0)
      att[((size_t)b * NN + i) * DIMX + h * DHH + d] = (LAM_A / 512.f) * vsum[d];
  }
  __syncthreads();

  int grp = lane >> 4;
  int li  = lane & 15;

  for (int base = wave * 4; base < nr; base += 16) {
    int ridx = base + grp;
    bool rok = ridx < nr;
    int i = i0 + ract[rok ? ridx : 0];
    const float* qi = q + ((size_t)bh * NN + i) * QS;
    float4 q0 = *(const float4*)(qi);
    float4 q1 = *(const float4*)(qi + 4);
    float4 q2 = *(const float4*)(qi + 8);
    float qreg[DHH] = {q0.x*SCALE, q0.y*SCALE, q0.z*SCALE, q0.w*SCALE,
                       q1.x*SCALE, q1.y*SCALE, q1.z*SCALE, q1.w*SCALE,
                       q2.x*SCALE, q2.y*SCALE, q2.z*SCALE, q2.w*SCALE,
                       qi[12]*SCALE};
    const float* adjr = adj + ((size_t)b * NN + i) * NN;

    float s[NU], aj[NU];
    float mx = -FLT_MAX;
#pragma unroll
    for (int u = 0; u < NU; ++u) {
      if (u * 16 < na) {  // wave-uniform branch
        int t = u * 16 + li;
        ushort8 ka = k0s[t];
        ushort8 kc = k1s[t];
        aj[u] = adjr[jact[t]];  // prefetched, consumed after softmax
        float dot = 0.f;
#pragma unroll
        for (int d = 0; d < 8; ++d) dot = fmaf(qreg[d], bf2f(ka[d]), dot);
#pragma unroll
        for (int d = 0; d < 5; ++d) dot = fmaf(qreg[8 + d], bf2f(kc[d]), dot);
        s[u] = (t < na) ? dot : -FLT_MAX;
        mx = fmaxf(mx, s[u]);
      }
    }
#pragma unroll
    for (int off = 1; off < 16; off <<= 1) mx = fmaxf(mx, __shfl_xor(mx, off));

    float sum = 0.f;
#pragma unroll
    for (int u = 0; u < NU; ++u) {
      if (u * 16 < na) {
        float p = __expf(s[u] - mx);
        s[u] = p;
        sum += p;
      }
    }
#pragma unroll
    for (int off = 1; off < 16; off <<= 1) sum += __shfl_xor(sum, off);
    float inv = LAM_A / sum;

    float acc[DHH];
#pragma unroll
    for (int d = 0; d < DHH; ++d) acc[d] = 0.f;
#pragma unroll
    for (int u = 0; u < NU; ++u) {
      if (u * 16 < na) {
        int t = u * 16 + li;
        ushort8 va = v0s[t];
        ushort8 vc = v1s[t];
        float wu = fmaf(LAM_G, aj[u], s[u] * inv);  // tail rows: v==0 -> 0
#pragma unroll
        for (int d = 0; d < 8; ++d) acc[d] = fmaf(wu, bf2f(va[d]), acc[d]);
#pragma unroll
        for (int d = 0; d < 5; ++d) acc[8 + d] = fmaf(wu, bf2f(vc[d]), acc[8 + d]);
      }
    }
#pragma unroll
    for (int off = 1; off < 16; off <<= 1) {
#pragma unroll
      for (int d = 0; d < DHH; ++d) acc[d] += __shfl_xor(acc[d], off);
    }

    if (rok && li == 0) {
#pragma unroll
      for (int d = 0; d < DHH; ++d)
        att[((size_t)b * NN + i) * DIMX + h * DHH + d] = acc[d];
    }
  }
}

// ---------------- Output projection: (B*N,78) @ (78,78) + b ----------------
// block = 320 threads (5 waves), 32 rows/block, thread = 2 rows x 4 cols.
__global__ __launch_bounds__(320) void proj_kernel(
    const float* __restrict__ att, const float* __restrict__ Wout,
    const float* __restrict__ bout, float* __restrict__ out) {
  __shared__ float Ws[DIMX][80];   // padded cols
  __shared__ float as[32][82];     // stride 82: conflict-free row reads
  __shared__ float bs[80];
  int tid = threadIdx.x;
  for (int e = tid; e < DIMX * 80; e += 320) {
    int r = e / 80, c = e % 80;
    Ws[r][c] = (c < DIMX) ? Wout[r * DIMX + c] : 0.f;
  }
  if (tid < 80) bs[tid] = (tid < DIMX) ? bout[tid] : 0.f;
  size_t row0 = (size_t)blockIdx.x * 32;
  for (int e = tid; e < 32 * DIMX; e += 320)
    as[e / DIMX][e % DIMX] = att[row0 * DIMX + e];
  __syncthreads();

  int r2 = tid / 20;   // 0..15 -> rows r2*2, r2*2+1
  int cq = tid % 20;   // 0..19 -> cols cq*4..cq*4+3 (last quad: 2 pad)
  int c0 = cq * 4;
  float acc0[4], acc1[4];
#pragma unroll
  for (int kk = 0; kk < 4; ++kk) { acc0[kk] = bs[c0 + kk]; acc1[kk] = bs[c0 + kk]; }

#pragma unroll 6
  for (int d = 0; d < DIMX; ++d) {
    float4 w = *(const float4*)&Ws[d][c0];
    float a0 = as[r2 * 2 + 0][d];
    float a1 = as[r2 * 2 + 1][d];
    acc0[0] = fmaf(a0, w.x, acc0[0]); acc0[1] = fmaf(a0, w.y, acc0[1]);
    acc0[2] = fmaf(a0, w.z, acc0[2]); acc0[3] = fmaf(a0, w.w, acc0[3]);
    acc1[0] = fmaf(a1, w.x, acc1[0]); acc1[1] = fmaf(a1, w.y, acc1[1]);
    acc1[2] = fmaf(a1, w.z, acc1[2]); acc1[3] = fmaf(a1, w.w, acc1[3]);
  }

  size_t r0o = (row0 + r2 * 2) * (size_t)DIMX;
  *(float2*)&out[r0o + c0]        = make_float2(acc0[0], acc0[1]);
  *(float2*)&out[r0o + DIMX + c0] = make_float2(acc1[0], acc1[1]);
  if (cq < 19) {
    *(float2*)&out[r0o + c0 + 2]        = make_float2(acc0[2], acc0[3]);
    *(float2*)&out[r0o + DIMX + c0 + 2] = make_float2(acc1[2], acc1[3]);
  }
}

extern "C" void kernel_launch(void* const* d_in, const int* in_sizes, int n_in,
                              void* d_out, int out_size, void* d_ws, size_t ws_size,
                              hipStream_t stream) {
  const float* x    = (const float*)d_in[0];
  const int*   mask = (const int*)d_in[1];
  const float* adj  = (const float*)d_in[2];
  const float* Wqkv = (const float*)d_in[3];
  const float* Wout = (const float*)d_in[4];
  const float* bout = (const float*)d_in[5];
  float* out = (float*)d_out;

  const size_t qkv_elems = (size_t)BB * NH * NN * QS;  // 786,432 (padded)
  float* q   = (float*)d_ws;
  float* k   = q + qkv_elems;
  float* v   = k + qkv_elems;
  float* att = v + qkv_elems;  // B*N*78

  const int NQ = 59;
  int qkv_threads = (BB * NN / 4) * NQ;
  qkv_kernel<<<(qkv_threads + 255) / 256, 256, 0, stream>>>(x, Wqkv, q, k, v);
  attn_kernel<<<BB * NH * (NN / 64), 256, 0, stream>>>(q, k, v, mask, adj, att);
  proj_kernel<<<BB * NN / 32, 320, 0, stream>>>(att, Wout, bout, out);
}